// Round 9
// baseline (84.449 us; speedup 1.0000x reference)
//
#include <hip/hip_runtime.h>

#define NV 50000
#define NJ 24
#define NBETA 10
#define NP 207          // (24-1)*9
#define NROWS 150000    // NV*3
#define ROWGROUPS 37500 // NROWS/4

#define K1_BLOCKS 196   // blocks that produce J partials
#define VPB 32
#define GPB 24          // 4-row groups per block (96 rows = 32 vertices)
#define K3_BLOCKS 1563  // ceil(50000/32)

// ws layout (float offsets)
#define PARTIAL_OFF 0        // 196*72 = 14112 floats
#define M_OFF       14336    // 24*12 = 288 floats
#define CTR_OFF     14656    // 1 uint (byte offset 58624)

__device__ const int d_par[NJ] = {0,0,0,0,1,2,3,4,5,6,7,8,9,9,9,12,13,14,16,17,18,19,20,21};
__device__ const int d_lvl[NJ] = {0,1,1,1,2,2,2,3,3,3,4,4,4,4,4,5,5,5,6,6,7,7,8,8};

// ---------------------------------------------------------------------------
// k_mega: [all blocks] rodrigues -> lrotmin in LDS;
//         [blk<196] J-partials + counter post;
//         [blk==0] spin for 196 posts -> J reduce -> chain -> M to ws;
//         [all blocks] pose GEMV (R8 core) -> out = vposed + v_template.
// ---------------------------------------------------------------------------
__global__ __launch_bounds__(256, 4) void k_mega(
    const float* __restrict__ betas, const float* __restrict__ pose,
    const float* __restrict__ shapedirs, const float* __restrict__ v_template,
    const float* __restrict__ Jreg, const float* __restrict__ posedirs,
    float* __restrict__ ws, float* __restrict__ out)
{
    __shared__ float smem[8448];   // k1 phase: sd[7680] + vt[768]; block0 later overlays Jl/cs/Gl
    __shared__ float lrotl[NP];
    __shared__ float Rl[216];
    __shared__ float red[288];

    const int t = threadIdx.x;
    const int blk = blockIdx.x;
    const int lane = t & 63, wv = t >> 6;
    const int l16 = lane & 15, g = lane >> 4;

    // ---- A) rodrigues, all blocks (lrotmin depends only on pose) ----
    if (t < NJ) {
        const float x = pose[t * 3 + 0], y = pose[t * 3 + 1], z = pose[t * 3 + 2];
        const float ex = x + 1e-8f, ey = y + 1e-8f, ez = z + 1e-8f;
        const float theta = sqrtf(ex * ex + ey * ey + ez * ez);
        const float inv = 1.f / theta;
        const float rx = x * inv, ry = y * inv, rz = z * inv;
        const float c = cosf(theta), s = sinf(theta), omc = 1.f - c;
        Rl[t * 9 + 0] = c + omc * rx * rx;      Rl[t * 9 + 1] = omc * rx * ry - s * rz;
        Rl[t * 9 + 2] = omc * rx * rz + s * ry; Rl[t * 9 + 3] = omc * ry * rx + s * rz;
        Rl[t * 9 + 4] = c + omc * ry * ry;      Rl[t * 9 + 5] = omc * ry * rz - s * rx;
        Rl[t * 9 + 6] = omc * rz * rx - s * ry; Rl[t * 9 + 7] = omc * rz * ry + s * rx;
        Rl[t * 9 + 8] = c + omc * rz * rz;
    }
    __syncthreads();
    if (t >= 9 && t < 216) {
        const int q = t % 9;
        lrotl[t - 9] = Rl[t] - ((q == 0 || q == 4 || q == 8) ? 1.f : 0.f);
    }

    // ---- B) J partials (blocks 0..195) ----
    if (blk < K1_BLOCKS) {
        float* sd = smem;           // 256*30
        float* vt = smem + 7680;    // 256*3
        const int vbase = blk * 256;
        const int nv    = min(256, NV - vbase);   // 256, or 80 for last block
        {
            const int nf4 = (nv * 30) >> 2;
            const float4* sdg = (const float4*)(shapedirs + (size_t)vbase * 30);
            for (int i = t; i < nf4; i += 256) ((float4*)sd)[i] = sdg[i];
            const float* vtg = v_template + (size_t)vbase * 3;
            const int nf3 = nv * 3;
            for (int i = t; i < nf3; i += 256) vt[i] = vtg[i];
        }
        __syncthreads();

        float accJ[72];
#pragma unroll
        for (int q = 0; q < 72; q++) accJ[q] = 0.f;

        const int v = vbase + t;
        if (v < NV) {
            float vs0 = vt[t * 3 + 0], vs1 = vt[t * 3 + 1], vs2 = vt[t * 3 + 2];
#pragma unroll
            for (int i = 0; i < NBETA; i++) {
                const float b = betas[i];
                vs0 += sd[t * 30 + 0 * 10 + i] * b;
                vs1 += sd[t * 30 + 1 * 10 + i] * b;
                vs2 += sd[t * 30 + 2 * 10 + i] * b;
            }
#pragma unroll
            for (int j = 0; j < NJ; j++) {
                const float w = Jreg[(size_t)j * NV + v];
                accJ[j * 3 + 0] += w * vs0;
                accJ[j * 3 + 1] += w * vs1;
                accJ[j * 3 + 2] += w * vs2;
            }
        }

#pragma unroll
        for (int q = 0; q < 72; q++) {
            float x = accJ[q];
#pragma unroll
            for (int m = 1; m < 64; m <<= 1) x += __shfl_xor(x, m);
            if (lane == 0) red[wv * 72 + q] = x;
        }
        __syncthreads();
        if (t < 72)
            ws[PARTIAL_OFF + blk * 72 + t] = red[t] + red[72 + t] + red[144 + t] + red[216 + t];
        __threadfence();
        __syncthreads();
        if (t == 0)
            __hip_atomic_fetch_add((unsigned int*)(ws + CTR_OFF), 1u,
                                   __ATOMIC_RELEASE, __HIP_MEMORY_SCOPE_AGENT);
    }

    // ---- C) block 0: wait for partials, reduce J, chain, write M ----
    if (blk == 0) {
        if (t == 0) {
            while (__hip_atomic_load((const unsigned int*)(ws + CTR_OFF),
                                     __ATOMIC_ACQUIRE, __HIP_MEMORY_SCOPE_AGENT)
                   < (unsigned int)K1_BLOCKS) {
                __builtin_amdgcn_s_sleep(8);
            }
        }
        __syncthreads();
        __threadfence();

        float* Jl = smem;          // 72
        float* cs = smem + 128;    // 216
        float* Gl = smem + 512;    // 288

        if (t < 216) {
            const int q = t % 72, chunk = t / 72;
            const int b0 = chunk * 66;
            const int b1 = min(K1_BLOCKS, b0 + 66);
            float s = 0.f;
            volatile const float* vp = ws + PARTIAL_OFF;
            for (int b = b0; b < b1; b++) s += vp[b * 72 + q];
            cs[chunk * 72 + q] = s;
        }
        __syncthreads();
        if (t < 72) Jl[t] = cs[t] + cs[72 + t] + cs[144 + t];
        __syncthreads();

        for (int L = 0; L < 9; L++) {
            if (t < NJ && d_lvl[t] == L) {
                if (t == 0) {
#pragma unroll
                    for (int r = 0; r < 3; r++) {
                        Gl[r * 4 + 0] = Rl[r * 3 + 0];
                        Gl[r * 4 + 1] = Rl[r * 3 + 1];
                        Gl[r * 4 + 2] = Rl[r * 3 + 2];
                        Gl[r * 4 + 3] = Jl[r];
                    }
                } else {
                    const int p = d_par[t];
                    const float tx = Jl[t * 3 + 0] - Jl[p * 3 + 0];
                    const float ty = Jl[t * 3 + 1] - Jl[p * 3 + 1];
                    const float tz = Jl[t * 3 + 2] - Jl[p * 3 + 2];
#pragma unroll
                    for (int r = 0; r < 3; r++) {
                        const float g0 = Gl[p * 12 + r * 4 + 0];
                        const float g1 = Gl[p * 12 + r * 4 + 1];
                        const float g2 = Gl[p * 12 + r * 4 + 2];
                        const float g3 = Gl[p * 12 + r * 4 + 3];
                        Gl[t * 12 + r * 4 + 0] = g0 * Rl[t * 9 + 0] + g1 * Rl[t * 9 + 3] + g2 * Rl[t * 9 + 6];
                        Gl[t * 12 + r * 4 + 1] = g0 * Rl[t * 9 + 1] + g1 * Rl[t * 9 + 4] + g2 * Rl[t * 9 + 7];
                        Gl[t * 12 + r * 4 + 2] = g0 * Rl[t * 9 + 2] + g1 * Rl[t * 9 + 5] + g2 * Rl[t * 9 + 8];
                        Gl[t * 12 + r * 4 + 3] = g0 * tx + g1 * ty + g2 * tz + g3;
                    }
                }
            }
            __syncthreads();
        }

        if (t < NJ) {
            const float jx = Jl[t * 3 + 0], jy = Jl[t * 3 + 1], jz = Jl[t * 3 + 2];
#pragma unroll
            for (int r = 0; r < 3; r++) {
                const float g0 = Gl[t * 12 + r * 4 + 0];
                const float g1 = Gl[t * 12 + r * 4 + 1];
                const float g2 = Gl[t * 12 + r * 4 + 2];
                const float g3 = Gl[t * 12 + r * 4 + 3];
                ws[M_OFF + t * 12 + r * 4 + 0] = g0;
                ws[M_OFF + t * 12 + r * 4 + 1] = g1;
                ws[M_OFF + t * 12 + r * 4 + 2] = g2;
                ws[M_OFF + t * 12 + r * 4 + 3] = g3 - (g0 * jx + g1 * jy + g2 * jz);
            }
        }
    }

    __syncthreads();   // lrotl ready for all blocks; smem overlay settled

    // ---- D) pose GEMV (R8 core), write vposed + v_template to out ----
    float lrk[12];
#pragma unroll
    for (int k = 0; k < 12; k++) lrk[k] = lrotl[k * 16 + l16];
    const float lr12 = (l16 < 15) ? lrotl[192 + l16] : 0.f;
    const float bet  = (l16 < NBETA) ? betas[l16] : 0.f;

    const int gbase = blk * GPB + wv * 6;
    float pv[6][12];
    float tv[6], sv[6];

    if (gbase + 5 < ROWGROUPS) {
#pragma unroll
        for (int i = 0; i < 6; i++) {
            const int row = (gbase + i) * 4 + g;
            const float* pd = posedirs + (size_t)row * NP;
#pragma unroll
            for (int k = 0; k < 12; k++) pv[i][k] = pd[k * 16 + l16];
            tv[i] = (l16 < 15) ? pd[192 + l16] : 0.f;
            sv[i] = (l16 < NBETA) ? shapedirs[(size_t)row * NBETA + l16] : 0.f;
        }
    } else {
#pragma unroll
        for (int i = 0; i < 6; i++) {
            const bool ok = (gbase + i) < ROWGROUPS;
            const int row = ok ? ((gbase + i) * 4 + g) : 0;
            const float* pd = posedirs + (size_t)row * NP;
#pragma unroll
            for (int k = 0; k < 12; k++) pv[i][k] = ok ? pd[k * 16 + l16] : 0.f;
            tv[i] = (ok && l16 < 15) ? pd[192 + l16] : 0.f;
            sv[i] = (ok && l16 < NBETA) ? shapedirs[(size_t)row * NBETA + l16] : 0.f;
        }
    }

    float acc[6];
#pragma unroll
    for (int i = 0; i < 6; i++) {
        float a = tv[i] * lr12 + sv[i] * bet;
#pragma unroll
        for (int k = 0; k < 12; k++) a += pv[i][k] * lrk[k];
        acc[i] = a;
    }
#pragma unroll
    for (int m = 1; m < 16; m <<= 1) {
#pragma unroll
        for (int i = 0; i < 6; i++) acc[i] += __shfl_xor(acc[i], m);
    }
    if (l16 == 0) {
#pragma unroll
        for (int i = 0; i < 6; i++) {
            const int grp = gbase + i;
            if (grp < ROWGROUPS) {
                const int row = grp * 4 + g;
                out[row] = acc[i] + v_template[row];
            }
        }
    }
}

// ---------------------------------------------------------------------------
// k_skin: one vertex per thread, in-place on out (vposed -> final v)
// ---------------------------------------------------------------------------
__global__ __launch_bounds__(256) void k_skin(
    const float* __restrict__ trans, const float* __restrict__ weights,
    const float* __restrict__ ws, float* __restrict__ out)
{
    __shared__ float Ml[288];
    const int t = threadIdx.x;
    Ml[t] = ws[M_OFF + t];
    if (t < 32) Ml[256 + t] = ws[M_OFF + 256 + t];
    __syncthreads();

    const int v = blockIdx.x * 256 + t;
    if (v >= NV) return;

    const float4* w4 = (const float4*)(weights + (size_t)v * 24);
    float wj[24];
#pragma unroll
    for (int q = 0; q < 6; q++) {
        const float4 w = w4[q];
        wj[q * 4 + 0] = w.x; wj[q * 4 + 1] = w.y;
        wj[q * 4 + 2] = w.z; wj[q * 4 + 3] = w.w;
    }

    float T[12];
#pragma unroll
    for (int q = 0; q < 12; q++) T[q] = 0.f;
#pragma unroll
    for (int j = 0; j < NJ; j++) {
        const float w = wj[j];
#pragma unroll
        for (int q = 0; q < 12; q++) T[q] += w * Ml[j * 12 + q];
    }

    const float p0 = out[(size_t)v * 3 + 0];
    const float p1 = out[(size_t)v * 3 + 1];
    const float p2 = out[(size_t)v * 3 + 2];
    out[(size_t)v * 3 + 0] = T[0] * p0 + T[1] * p1 + T[2]  * p2 + T[3]  + trans[0];
    out[(size_t)v * 3 + 1] = T[4] * p0 + T[5] * p1 + T[6]  * p2 + T[7]  + trans[1];
    out[(size_t)v * 3 + 2] = T[8] * p0 + T[9] * p1 + T[10] * p2 + T[11] + trans[2];
}

extern "C" void kernel_launch(void* const* d_in, const int* in_sizes, int n_in,
                              void* d_out, int out_size, void* d_ws, size_t ws_size,
                              hipStream_t stream) {
    const float* betas      = (const float*)d_in[0];
    const float* pose       = (const float*)d_in[1];
    const float* trans      = (const float*)d_in[2];
    const float* shapedirs  = (const float*)d_in[3];
    const float* v_template = (const float*)d_in[4];
    const float* Jreg       = (const float*)d_in[5];
    const float* weights    = (const float*)d_in[6];
    const float* posedirs   = (const float*)d_in[7];
    float* ws  = (float*)d_ws;
    float* out = (float*)d_out;

    // reset the cross-block counter every call (graph-replay safe)
    hipMemsetAsync((char*)d_ws + CTR_OFF * sizeof(float), 0, sizeof(unsigned int), stream);

    k_mega<<<dim3(K3_BLOCKS), dim3(256), 0, stream>>>(
        betas, pose, shapedirs, v_template, Jreg, posedirs, ws, out);
    k_skin<<<dim3((NV + 255) / 256), dim3(256), 0, stream>>>(trans, weights, ws, out);
}

// Round 10
// 52.556 us; speedup vs baseline: 1.6069x; 1.6069x over previous
//
#include <hip/hip_runtime.h>

#define NV 50000
#define NJ 24
#define NBETA 10
#define NP 207          // (24-1)*9
#define NROWS 150000    // NV*3
#define ROWGROUPS 37500 // NROWS/4

#define K1_BLOCKS 196   // blocks that also produce J partials
#define GPB 24          // 4-row groups per block (96 rows = 32 vertices)
#define K3_BLOCKS 1563  // ceil(50000/32)
#define KB_BLOCKS 196   // skin blocks: 196*256 = 50176 >= 50000

__device__ const int d_par[NJ] = {0,0,0,0,1,2,3,4,5,6,7,8,9,9,9,12,13,14,16,17,18,19,20,21};
__device__ const int d_lvl[NJ] = {0,1,1,1,2,2,2,3,3,3,4,4,4,4,4,5,5,5,6,6,7,7,8,8};

// ---------------------------------------------------------------------------
// k_front: [all blocks] rodrigues -> lrotmin (LDS);
//          [blk<196] J-partials (low-VGPR wave-per-6-joints form) -> ws;
//          [all blocks] R8 GEMV core -> out = vposed + v_template.
// LDS ~4.8KB, VGPR target <=64 -> 8 blocks/CU.
// ---------------------------------------------------------------------------
__global__ __launch_bounds__(256, 4) void k_front(
    const float* __restrict__ betas, const float* __restrict__ pose,
    const float* __restrict__ shapedirs, const float* __restrict__ v_template,
    const float* __restrict__ Jreg, const float* __restrict__ posedirs,
    float* __restrict__ ws, float* __restrict__ out)
{
    __shared__ float Rl[216];
    __shared__ float lrotl[NP];
    __shared__ float bet[NBETA];
    __shared__ float vsl[768];     // 256 vertices x 3 (v_shaped)

    const int t = threadIdx.x;
    const int blk = blockIdx.x;
    const int lane = t & 63, wv = t >> 6;
    const int l16 = lane & 15, g = lane >> 4;

    // ---- A) rodrigues (all blocks; depends only on pose) ----
    if (t < NJ) {
        const float x = pose[t * 3 + 0], y = pose[t * 3 + 1], z = pose[t * 3 + 2];
        const float ex = x + 1e-8f, ey = y + 1e-8f, ez = z + 1e-8f;
        const float theta = sqrtf(ex * ex + ey * ey + ez * ez);
        const float inv = 1.f / theta;
        const float rx = x * inv, ry = y * inv, rz = z * inv;
        const float c = cosf(theta), s = sinf(theta), omc = 1.f - c;
        Rl[t * 9 + 0] = c + omc * rx * rx;      Rl[t * 9 + 1] = omc * rx * ry - s * rz;
        Rl[t * 9 + 2] = omc * rx * rz + s * ry; Rl[t * 9 + 3] = omc * ry * rx + s * rz;
        Rl[t * 9 + 4] = c + omc * ry * ry;      Rl[t * 9 + 5] = omc * ry * rz - s * rx;
        Rl[t * 9 + 6] = omc * rz * rx - s * ry; Rl[t * 9 + 7] = omc * rz * ry + s * rx;
        Rl[t * 9 + 8] = c + omc * rz * rz;
    }
    if (t >= 32 && t < 32 + NBETA) bet[t - 32] = betas[t - 32];
    __syncthreads();
    if (t >= 9 && t < 216) {
        const int q = t % 9;
        lrotl[t - 9] = Rl[t] - ((q == 0 || q == 4 || q == 8) ? 1.f : 0.f);
    }

    // ---- B) J-partials (blocks 0..195), low-VGPR form ----
    if (blk < K1_BLOCKS) {
        const int vbase = blk * 256;
        const int v = vbase + t;
        float vs0 = 0.f, vs1 = 0.f, vs2 = 0.f;
        if (v < NV) {
            vs0 = v_template[(size_t)v * 3 + 0];
            vs1 = v_template[(size_t)v * 3 + 1];
            vs2 = v_template[(size_t)v * 3 + 2];
            const float* sd = shapedirs + (size_t)v * 30;
#pragma unroll
            for (int i = 0; i < NBETA; i++) {
                const float b = bet[i];
                vs0 += sd[i] * b;
                vs1 += sd[10 + i] * b;
                vs2 += sd[20 + i] * b;
            }
        }
        vsl[t * 3 + 0] = vs0; vsl[t * 3 + 1] = vs1; vsl[t * 3 + 2] = vs2;
        __syncthreads();

        // wave wv owns joints [wv*6, wv*6+6)
        const int j0 = wv * 6;
        float acc[6][3];
#pragma unroll
        for (int jj = 0; jj < 6; jj++) { acc[jj][0] = 0.f; acc[jj][1] = 0.f; acc[jj][2] = 0.f; }
#pragma unroll
        for (int chunk = 0; chunk < 4; chunk++) {
            const int vl = chunk * 64 + lane;
            const float p0 = vsl[vl * 3 + 0], p1 = vsl[vl * 3 + 1], p2 = vsl[vl * 3 + 2];
            const int v2 = vbase + vl;
            const bool ok = v2 < NV;
#pragma unroll
            for (int jj = 0; jj < 6; jj++) {
                const float w = ok ? Jreg[(size_t)(j0 + jj) * NV + v2] : 0.f;
                acc[jj][0] += w * p0; acc[jj][1] += w * p1; acc[jj][2] += w * p2;
            }
        }
#pragma unroll
        for (int m = 1; m < 64; m <<= 1) {
#pragma unroll
            for (int jj = 0; jj < 6; jj++) {
                acc[jj][0] += __shfl_xor(acc[jj][0], m);
                acc[jj][1] += __shfl_xor(acc[jj][1], m);
                acc[jj][2] += __shfl_xor(acc[jj][2], m);
            }
        }
        if (lane == 0) {
#pragma unroll
            for (int jj = 0; jj < 6; jj++) {
                ws[blk * 72 + (j0 + jj) * 3 + 0] = acc[jj][0];
                ws[blk * 72 + (j0 + jj) * 3 + 1] = acc[jj][1];
                ws[blk * 72 + (j0 + jj) * 3 + 2] = acc[jj][2];
            }
        }
    }
    __syncthreads();   // lrotl ready for all; vsl dead

    // ---- C) pose GEMV (R8 core) -> out ----
    float lrk[12];
#pragma unroll
    for (int k = 0; k < 12; k++) lrk[k] = lrotl[k * 16 + l16];
    const float lr12 = (l16 < 15) ? lrotl[192 + l16] : 0.f;
    const float bsc  = (l16 < NBETA) ? bet[l16] : 0.f;

    const int gbase = blk * GPB + wv * 6;
    float pv[6][12];
    float tv[6], sv[6];

    if (gbase + 5 < ROWGROUPS) {
#pragma unroll
        for (int i = 0; i < 6; i++) {
            const int row = (gbase + i) * 4 + g;
            const float* pd = posedirs + (size_t)row * NP;
#pragma unroll
            for (int k = 0; k < 12; k++) pv[i][k] = pd[k * 16 + l16];
            tv[i] = (l16 < 15) ? pd[192 + l16] : 0.f;
            sv[i] = (l16 < NBETA) ? shapedirs[(size_t)row * NBETA + l16] : 0.f;
        }
    } else {
#pragma unroll
        for (int i = 0; i < 6; i++) {
            const bool ok = (gbase + i) < ROWGROUPS;
            const int row = ok ? ((gbase + i) * 4 + g) : 0;
            const float* pd = posedirs + (size_t)row * NP;
#pragma unroll
            for (int k = 0; k < 12; k++) pv[i][k] = ok ? pd[k * 16 + l16] : 0.f;
            tv[i] = (ok && l16 < 15) ? pd[192 + l16] : 0.f;
            sv[i] = (ok && l16 < NBETA) ? shapedirs[(size_t)row * NBETA + l16] : 0.f;
        }
    }

    float acc[6];
#pragma unroll
    for (int i = 0; i < 6; i++) {
        float a = tv[i] * lr12 + sv[i] * bsc;
#pragma unroll
        for (int k = 0; k < 12; k++) a += pv[i][k] * lrk[k];
        acc[i] = a;
    }
#pragma unroll
    for (int m = 1; m < 16; m <<= 1) {
#pragma unroll
        for (int i = 0; i < 6; i++) acc[i] += __shfl_xor(acc[i], m);
    }
    if (l16 == 0) {
#pragma unroll
        for (int i = 0; i < 6; i++) {
            const int grp = gbase + i;
            if (grp < ROWGROUPS) {
                const int row = grp * 4 + g;
                out[row] = acc[i] + v_template[row];
            }
        }
    }
}

// ---------------------------------------------------------------------------
// k_back: each of 196 blocks redundantly reduces partials -> J, runs the
// kinematic chain -> M (LDS), then skins its 256 vertices in-place on out.
// ---------------------------------------------------------------------------
__global__ __launch_bounds__(256) void k_back(
    const float* __restrict__ pose, const float* __restrict__ trans,
    const float* __restrict__ weights, const float* __restrict__ ws,
    float* __restrict__ out)
{
    __shared__ float Rl[216];
    __shared__ float Jl[72];
    __shared__ float cs[216];
    __shared__ float Gl[288];
    const int t = threadIdx.x;

    // rodrigues
    if (t < NJ) {
        const float x = pose[t * 3 + 0], y = pose[t * 3 + 1], z = pose[t * 3 + 2];
        const float ex = x + 1e-8f, ey = y + 1e-8f, ez = z + 1e-8f;
        const float theta = sqrtf(ex * ex + ey * ey + ez * ez);
        const float inv = 1.f / theta;
        const float rx = x * inv, ry = y * inv, rz = z * inv;
        const float c = cosf(theta), s = sinf(theta), omc = 1.f - c;
        Rl[t * 9 + 0] = c + omc * rx * rx;      Rl[t * 9 + 1] = omc * rx * ry - s * rz;
        Rl[t * 9 + 2] = omc * rx * rz + s * ry; Rl[t * 9 + 3] = omc * ry * rx + s * rz;
        Rl[t * 9 + 4] = c + omc * ry * ry;      Rl[t * 9 + 5] = omc * ry * rz - s * rx;
        Rl[t * 9 + 6] = omc * rz * rx - s * ry; Rl[t * 9 + 7] = omc * rz * ry + s * rx;
        Rl[t * 9 + 8] = c + omc * rz * rz;
    }

    // reduce partials (3 chunks x 72)
    if (t < 216) {
        const int q = t % 72, chunk = t / 72;
        const int b0 = chunk * 66;
        const int b1 = min(K1_BLOCKS, b0 + 66);
        float s = 0.f;
        for (int b = b0; b < b1; b++) s += ws[b * 72 + q];
        cs[chunk * 72 + q] = s;
    }
    __syncthreads();
    if (t < 72) Jl[t] = cs[t] + cs[72 + t] + cs[144 + t];
    __syncthreads();

    // kinematic chain
    for (int L = 0; L < 9; L++) {
        if (t < NJ && d_lvl[t] == L) {
            if (t == 0) {
#pragma unroll
                for (int r = 0; r < 3; r++) {
                    Gl[r * 4 + 0] = Rl[r * 3 + 0];
                    Gl[r * 4 + 1] = Rl[r * 3 + 1];
                    Gl[r * 4 + 2] = Rl[r * 3 + 2];
                    Gl[r * 4 + 3] = Jl[r];
                }
            } else {
                const int p = d_par[t];
                const float tx = Jl[t * 3 + 0] - Jl[p * 3 + 0];
                const float ty = Jl[t * 3 + 1] - Jl[p * 3 + 1];
                const float tz = Jl[t * 3 + 2] - Jl[p * 3 + 2];
#pragma unroll
                for (int r = 0; r < 3; r++) {
                    const float g0 = Gl[p * 12 + r * 4 + 0];
                    const float g1 = Gl[p * 12 + r * 4 + 1];
                    const float g2 = Gl[p * 12 + r * 4 + 2];
                    const float g3 = Gl[p * 12 + r * 4 + 3];
                    Gl[t * 12 + r * 4 + 0] = g0 * Rl[t * 9 + 0] + g1 * Rl[t * 9 + 3] + g2 * Rl[t * 9 + 6];
                    Gl[t * 12 + r * 4 + 1] = g0 * Rl[t * 9 + 1] + g1 * Rl[t * 9 + 4] + g2 * Rl[t * 9 + 7];
                    Gl[t * 12 + r * 4 + 2] = g0 * Rl[t * 9 + 2] + g1 * Rl[t * 9 + 5] + g2 * Rl[t * 9 + 8];
                    Gl[t * 12 + r * 4 + 3] = g0 * tx + g1 * ty + g2 * tz + g3;
                }
            }
        }
        __syncthreads();
    }

    // M = G with corrected translation column (in place, t-local)
    if (t < NJ) {
        const float jx = Jl[t * 3 + 0], jy = Jl[t * 3 + 1], jz = Jl[t * 3 + 2];
#pragma unroll
        for (int r = 0; r < 3; r++) {
            const float g0 = Gl[t * 12 + r * 4 + 0];
            const float g1 = Gl[t * 12 + r * 4 + 1];
            const float g2 = Gl[t * 12 + r * 4 + 2];
            Gl[t * 12 + r * 4 + 3] -= g0 * jx + g1 * jy + g2 * jz;
        }
    }
    __syncthreads();

    // skinning, in place on out
    const int v = blockIdx.x * 256 + t;
    if (v >= NV) return;

    const float4* w4 = (const float4*)(weights + (size_t)v * 24);
    float wj[24];
#pragma unroll
    for (int q = 0; q < 6; q++) {
        const float4 w = w4[q];
        wj[q * 4 + 0] = w.x; wj[q * 4 + 1] = w.y;
        wj[q * 4 + 2] = w.z; wj[q * 4 + 3] = w.w;
    }

    float T[12];
#pragma unroll
    for (int q = 0; q < 12; q++) T[q] = 0.f;
#pragma unroll
    for (int j = 0; j < NJ; j++) {
        const float w = wj[j];
#pragma unroll
        for (int q = 0; q < 12; q++) T[q] += w * Gl[j * 12 + q];
    }

    const float p0 = out[(size_t)v * 3 + 0];
    const float p1 = out[(size_t)v * 3 + 1];
    const float p2 = out[(size_t)v * 3 + 2];
    out[(size_t)v * 3 + 0] = T[0] * p0 + T[1] * p1 + T[2]  * p2 + T[3]  + trans[0];
    out[(size_t)v * 3 + 1] = T[4] * p0 + T[5] * p1 + T[6]  * p2 + T[7]  + trans[1];
    out[(size_t)v * 3 + 2] = T[8] * p0 + T[9] * p1 + T[10] * p2 + T[11] + trans[2];
}

extern "C" void kernel_launch(void* const* d_in, const int* in_sizes, int n_in,
                              void* d_out, int out_size, void* d_ws, size_t ws_size,
                              hipStream_t stream) {
    const float* betas      = (const float*)d_in[0];
    const float* pose       = (const float*)d_in[1];
    const float* trans      = (const float*)d_in[2];
    const float* shapedirs  = (const float*)d_in[3];
    const float* v_template = (const float*)d_in[4];
    const float* Jreg       = (const float*)d_in[5];
    const float* weights    = (const float*)d_in[6];
    const float* posedirs   = (const float*)d_in[7];
    float* ws  = (float*)d_ws;
    float* out = (float*)d_out;

    k_front<<<dim3(K3_BLOCKS), dim3(256), 0, stream>>>(
        betas, pose, shapedirs, v_template, Jreg, posedirs, ws, out);
    k_back<<<dim3(KB_BLOCKS), dim3(256), 0, stream>>>(pose, trans, weights, ws, out);
}